// Round 1
// 1207.213 us; speedup vs baseline: 1.0956x; 1.0956x over previous
//
#include <hip/hip_runtime.h>
#include <hip/hip_bf16.h>

#define DI __device__ __forceinline__

typedef float f32x4 __attribute__((ext_vector_type(4)));
typedef __bf16 bf16x8 __attribute__((ext_vector_type(8)));

// ---------------- workspace layout (bytes) ----------------
#define XB_OFF   0ll                      // [2048][8][8][512] bf16  = 134217728
#define W1_OFF   134217728ll              // [768][4608] bf16        = 7077888
#define W2_OFF   141295616ll              // [768][2304] bf16        = 3538944
#define Y1_OFF   144834560ll              // [73728][768] bf16       = 113246208
#define QKV_OFF  258080768ll              // 3 x [32768][256] bf16   = 50331648
#define SEG_OFF  308412416ll              // 18 ints
// aliases inside the Y1 region (only used after conv2 is done):
#define S_OFF    (Y1_OFF)                 // 4 x [2048][2048] f32 = 67108864
#define P_OFF    (Y1_OFF + 67108864ll)    // [2048][2048] bf16    = 8388608
#define VT_OFF   (Y1_OFF + 75497472ll)    // [4096][2048] bf16    = 16777216

DI unsigned short f2bf(float f) {
  union { float f; unsigned u; } v; v.f = f;
  return (unsigned short)((v.u + 0x7FFFu + ((v.u >> 16) & 1u)) >> 16);
}

// async global->LDS, 16B per lane; LDS dest is wave-uniform base + lane*16
DI void stage16(const void* g, void* l) {
  __builtin_amdgcn_global_load_lds(
      (const __attribute__((address_space(1))) void*)(unsigned long long)g,
      (__attribute__((address_space(3))) void*)(unsigned long long)l,
      16, 0, 0);
}

// BK=64 LDS tile: [128 rows][8 chunks of 16B]; row stride = 128 B = full 32-bank span,
// so bank group depends only on chunk. Phys chunk = logical ^ (row&7):
//  - read: quarter-wave (16 lanes, rows 0..15, same logical chunk) spreads over
//    8 bank groups 2-way -> free (m136).
//  - staging lane l covers row (l>>3), phys chunk (l&7) -> clog=(l&7)^((l>>3)&7).
DI void mma_step64(const unsigned short* lA, const unsigned short* lB,
                   f32x4 acc[4][4], int lane, int wm, int wn) {
  const int r15 = lane & 15;
  const int cb = lane >> 4;            // k-subchunk within a 32-wide half
  const int rx = r15 & 7;
#pragma unroll
  for (int kh = 0; kh < 2; kh++) {
    const int ph = (kh * 4 + cb) ^ rx;
    bf16x8 af[4], bfr[4];
#pragma unroll
    for (int mi = 0; mi < 4; mi++)
      af[mi] = *(const bf16x8*)(lA + (wm * 64 + mi * 16 + r15) * 64 + ph * 8);
#pragma unroll
    for (int ni = 0; ni < 4; ni++)
      bfr[ni] = *(const bf16x8*)(lB + (wn * 64 + ni * 16 + r15) * 64 + ph * 8);
#pragma unroll
    for (int mi = 0; mi < 4; mi++)
#pragma unroll
      for (int ni = 0; ni < 4; ni++)
        acc[mi][ni] = __builtin_amdgcn_mfma_f32_16x16x32_bf16(af[mi], bfr[ni], acc[mi][ni], 0, 0, 0);
  }
}

// ---------------- segment offsets (+ int32/int64 layout detect) ----------------
__global__ void k_seg(const int* __restrict__ gid, int* __restrict__ seg) {
  __shared__ int cnt[16];
  int tid = threadIdx.x;
  if (tid < 16) cnt[tid] = 0;
  __syncthreads();
  int stride = (gid[2047] == 0) ? 2 : 1;
  for (int i = tid; i < 2048; i += 256) atomicAdd(&cnt[gid[i * stride]], 1);
  __syncthreads();
  if (tid == 0) {
    int s = 0;
    for (int g = 0; g < 16; g++) { seg[g] = s; s += cnt[g]; }
    seg[16] = s;
    seg[17] = stride;
  }
}

// ---------------- NCHW f32 -> NHWC bf16 ----------------
__global__ void k_convert_x(const float* __restrict__ x, unsigned short* __restrict__ xb) {
  __shared__ unsigned short t[64][66];   // [pixel][channel]
  const int n = blockIdx.x, cb = blockIdx.y;
  const int tid = threadIdx.x;
  const int cr = tid >> 6, p = tid & 63;
  const float* src = x + (n * 512 + cb * 64) * 64;
#pragma unroll
  for (int i = 0; i < 16; i++) {
    int c = i * 4 + cr;
    t[p][c] = f2bf(src[c * 64 + p]);
  }
  __syncthreads();
  unsigned* dst = (unsigned*)(xb + n * 32768 + cb * 64);
  const int pr = tid >> 5, c2 = tid & 31;
#pragma unroll
  for (int i = 0; i < 8; i++) {
    int p2 = i * 8 + pr;
    unsigned lo = t[p2][c2 * 2], hi = t[p2][c2 * 2 + 1];
    dst[p2 * 256 + c2] = lo | (hi << 16);
  }
}

// ---------------- weights: OIHW f32 -> [row][(ky,kx,cin)] bf16, fused w1+w2 ----------------
__global__ void k_convert_w(const float* __restrict__ qw1, const float* __restrict__ kw1,
                            const float* __restrict__ vw1, const float* __restrict__ qw2,
                            const float* __restrict__ kw2, const float* __restrict__ vw2,
                            unsigned short* __restrict__ w1t, unsigned short* __restrict__ w2t) {
  int idx = blockIdx.x * 256 + threadIdx.x;
  if (idx < 3538944) {                       // w1: 768 x 4608
    int row = idx / 4608, k = idx - row * 4608;
    int br = row >> 8, o = row & 255;
    int kk = k >> 9, cin = k & 511;
    int ky = kk / 3, kx = kk - ky * 3;
    const float* w = (br == 0) ? qw1 : (br == 1) ? kw1 : vw1;
    w1t[idx] = f2bf(w[((o * 512 + cin) * 3 + ky) * 3 + kx]);
  } else {                                   // w2: 768 x 2304
    idx -= 3538944;
    int row = idx / 2304, k = idx - row * 2304;
    int br = row >> 8, o = row & 255;
    int kk = k >> 8, c = k & 255;
    int ky = kk / 3, kx = kk - ky * 3;
    const float* w = (br == 0) ? qw2 : (br == 1) ? kw2 : vw2;
    w2t[idx] = f2bf(w[((o * 256 + c) * 3 + ky) * 3 + kx]);
  }
}

// kk/3 for kk in [0,9)
DI int conv1_aoff(int kt) {
  int kk = kt >> 4;
  int ky = (kk * 11) >> 5;
  int kx = kk - ky * 3;
  return (ky * 8 + kx) * 512 + (kt & 15) * 32;
}

// ---------------- conv1 implicit GEMM: M=73728 K=4608 N=768 ----------------
// 256x256 tile, BK=32, 8 waves (2M x 4N), 4-deep LDS ring (4 x 32 KiB), counted vmcnt.
// Schedule: T3+T4 (phase-split, vmcnt(8) once per K-tile, never 0 in main loop),
// T5 setprio around MFMA clusters, T1 bijective XCD swizzle (864 = 8*108).
// LDS swizzle: phys_chunk = logical ^ ((row>>1)&3), applied to gload source AND ds_read
// (both-sides involution, rule 21). Per-lane it is constant:
//   read: q4 ^ ((r15>>1)&3); stage: (lane&3) ^ ((lane>>3)&3).
__global__ __launch_bounds__(512, 2) void k_conv1(
    const unsigned short* __restrict__ xb, const unsigned short* __restrict__ w1t,
    const float* __restrict__ qb1, const float* __restrict__ kb1, const float* __restrict__ vb1,
    unsigned short* __restrict__ y1) {
  extern __shared__ __align__(16) unsigned short lds[];  // 4 x (A[256][32] | B[256][32]) = 131072 B
  const int bswz = (blockIdx.x & 7) * 108 + (blockIdx.x >> 3);
  const int mt = bswz / 3, nt = bswz - mt * 3;           // 288 mt x 3 nt
  const int tid = threadIdx.x;
  const int wave = tid >> 6, lane = tid & 63;
  const int wm = wave >> 2, wn = wave & 3;               // wave strip: rows wm*128, cols wn*64

  // ---- staging source pointers (pre-swizzled logical chunk; constant per lane) ----
  const int c8 = ((lane & 3) ^ ((lane >> 3) & 3)) * 8;
  const unsigned short* aSrc[2];
  const unsigned short* bSrc[2];
#pragma unroll
  for (int j = 0; j < 2; j++) {
    int rw = wave * 32 + j * 16 + (lane >> 2);
    int m = mt * 256 + rw;
    int n = m / 36, pix = m - n * 36;
    int oy = pix / 6, ox = pix - oy * 6;
    aSrc[j] = xb + ((n * 8 + oy) * 8 + ox) * 512 + c8;
    bSrc[j] = w1t + (nt * 256 + rw) * 4608 + c8;
  }

  // ---- fragment read offset (elements) ----
  const int r15 = lane & 15, q4 = lane >> 4;
  const int lo = r15 * 32 + ((q4 ^ ((r15 >> 1) & 3)) * 8);

  f32x4 acc[8][4];
  const f32x4 z = {0.f, 0.f, 0.f, 0.f};
#pragma unroll
  for (int i = 0; i < 8; i++)
#pragma unroll
    for (int j = 0; j < 4; j++) acc[i][j] = z;

#define C1_STAGE_A(ts_) do {                                        \
    const int ao_ = conv1_aoff(ts_);                                \
    unsigned short* d_ = lds + ((ts_) & 3) * 16384 + wave * 1024;   \
    stage16(aSrc[0] + ao_, d_);                                     \
    stage16(aSrc[1] + ao_, d_ + 512); } while (0)
#define C1_STAGE_B(ts_) do {                                        \
    const int bo_ = (ts_) * 32;                                     \
    unsigned short* d_ = lds + ((ts_) & 3) * 16384 + 8192 + wave * 1024; \
    stage16(bSrc[0] + bo_, d_);                                     \
    stage16(bSrc[1] + bo_, d_ + 512); } while (0)

  // prologue: tiles 0,1,2 in flight; wait tile0 (4 loads/tile -> vmcnt(8))
  C1_STAGE_A(0); C1_STAGE_B(0);
  C1_STAGE_A(1); C1_STAGE_B(1);
  C1_STAGE_A(2); C1_STAGE_B(2);
  asm volatile("s_waitcnt vmcnt(8)" ::: "memory");
  __builtin_amdgcn_s_barrier();
  asm volatile("" ::: "memory");

  for (int t = 0; t < 144; t++) {
    const unsigned short* La = lds + (t & 3) * 16384;
    const unsigned short* Lb = La + 8192;
    const int ts = t + 3;
    bf16x8 af[4], bv[4];
    // ---- phase 0: C rows wm*128 .. +63, full K=32; stage A of tile t+3 ----
#pragma unroll
    for (int fn = 0; fn < 4; fn++)
      bv[fn] = *(const bf16x8*)(Lb + (wn * 64 + fn * 16) * 32 + lo);
#pragma unroll
    for (int fm = 0; fm < 4; fm++)
      af[fm] = *(const bf16x8*)(La + (wm * 128 + fm * 16) * 32 + lo);
    if (ts < 144) C1_STAGE_A(ts);
    __builtin_amdgcn_s_barrier();
    asm volatile("" ::: "memory");
    __builtin_amdgcn_s_setprio(1);
#pragma unroll
    for (int fm = 0; fm < 4; fm++)
#pragma unroll
      for (int fn = 0; fn < 4; fn++)
        acc[fm][fn] = __builtin_amdgcn_mfma_f32_16x16x32_bf16(af[fm], bv[fn], acc[fm][fn], 0, 0, 0);
    __builtin_amdgcn_s_setprio(0);
    __builtin_amdgcn_s_barrier();
    asm volatile("" ::: "memory");
    // ---- phase 1: C rows wm*128+64 .. +127 (reuse bv); stage B of tile t+3 ----
#pragma unroll
    for (int fm = 0; fm < 4; fm++)
      af[fm] = *(const bf16x8*)(La + (wm * 128 + 64 + fm * 16) * 32 + lo);
    if (ts < 144) C1_STAGE_B(ts);
    __builtin_amdgcn_s_barrier();
    asm volatile("" ::: "memory");
    __builtin_amdgcn_s_setprio(1);
#pragma unroll
    for (int fm = 0; fm < 4; fm++)
#pragma unroll
      for (int fn = 0; fn < 4; fn++)
        acc[4 + fm][fn] = __builtin_amdgcn_mfma_f32_16x16x32_bf16(af[fm], bv[fn], acc[4 + fm][fn], 0, 0, 0);
    __builtin_amdgcn_s_setprio(0);
    // tile t+1 must be landed when any wave crosses this barrier:
    // outstanding allowed = tiles t+2,t+3 = 8 loads (tail drains 8 -> 4 -> 0)
    if (t < 141)       asm volatile("s_waitcnt vmcnt(8)" ::: "memory");
    else if (t == 141) asm volatile("s_waitcnt vmcnt(4)" ::: "memory");
    else if (t == 142) asm volatile("s_waitcnt vmcnt(0)" ::: "memory");
    __builtin_amdgcn_s_barrier();
    asm volatile("" ::: "memory");
  }
#undef C1_STAGE_A
#undef C1_STAGE_B

  // ---- epilogue: bias + relu -> y1 ----
  const float* bias = (nt == 0) ? qb1 : (nt == 1) ? kb1 : vb1;
#pragma unroll
  for (int fn = 0; fn < 4; fn++) {
    const int col = nt * 256 + wn * 64 + fn * 16 + r15;
    const float bvv = bias[col & 255];
#pragma unroll
    for (int fm = 0; fm < 8; fm++) {
      const int m0 = mt * 256 + wm * 128 + fm * 16 + q4 * 4;
#pragma unroll
      for (int r = 0; r < 4; r++) {
        float v = acc[fm][fn][r] + bvv;
        y1[(m0 + r) * 768 + col] = f2bf(v > 0.f ? v : 0.f);
      }
    }
  }
}

// ---------------- conv2 implicit GEMM per branch: M=32768 K=2304 N=256, BK=64 ----------------
// grid (nt=2 fast, br=3, mt=256): 6 consecutive blocks share one A-tile.
__global__ __launch_bounds__(256, 2) void k_conv2(
    const unsigned short* __restrict__ y1, const unsigned short* __restrict__ w2t,
    const float* __restrict__ qb2, const float* __restrict__ kb2, const float* __restrict__ vb2,
    unsigned short* __restrict__ qkv) {
  __shared__ __align__(16) unsigned short lA[128 * 64];
  __shared__ __align__(16) unsigned short lB[128 * 64];
  const int nt = blockIdx.x, br = blockIdx.y, mt = blockIdx.z;
  const int tid = threadIdx.x;
  const int wave = tid >> 6, lane = tid & 63;
  const int wm = wave >> 1, wn = wave & 1;

  const int clog = (lane & 7) ^ ((lane >> 3) & 7);
  const unsigned short* ap[4];
  const unsigned short* bp[4];
#pragma unroll
  for (int s = 0; s < 4; s++) {
    int m = mt * 128 + wave * 32 + s * 8 + (lane >> 3);
    int n = m >> 4, pix = m & 15;
    int oy = pix >> 2, ox = pix & 3;
    ap[s] = y1 + (n * 36 + oy * 6 + ox) * 768 + br * 256 + clog * 8;
    int r = br * 256 + nt * 128 + wave * 32 + s * 8 + (lane >> 3);
    bp[s] = w2t + r * 2304 + clog * 8;
  }

  f32x4 acc[4][4];
  const f32x4 z = {0.f, 0.f, 0.f, 0.f};
#pragma unroll
  for (int i = 0; i < 4; i++)
#pragma unroll
    for (int j = 0; j < 4; j++) acc[i][j] = z;

  for (int kt = 0; kt < 36; kt++) {
    int kk = kt >> 2;
    int ky = kk / 3, kx = kk - ky * 3;
    int aoff = (ky * 6 + kx) * 768 + (kt & 3) * 64;
    int boff = kt * 64;
    __syncthreads();
#pragma unroll
    for (int s = 0; s < 4; s++) {
      stage16(ap[s] + aoff, lA + (wave * 32 + s * 8) * 64);
      stage16(bp[s] + boff, lB + (wave * 32 + s * 8) * 64);
    }
    __syncthreads();
    mma_step64(lA, lB, acc, lane, wm, wn);
  }

  const float* bias = (br == 0) ? qb2 : (br == 1) ? kb2 : vb2;
  unsigned short* outb = qkv + br * 8388608;
  const int r15 = lane & 15, q4 = lane >> 4;
#pragma unroll
  for (int ni = 0; ni < 4; ni++) {
    int o = nt * 128 + wn * 64 + ni * 16 + r15;
    float bv = bias[o];
#pragma unroll
    for (int mi = 0; mi < 4; mi++) {
      int m0 = mt * 128 + wm * 64 + mi * 16 + q4 * 4;
#pragma unroll
      for (int r = 0; r < 4; r++) {
        float v = acc[mi][ni][r] + bv;
        outb[(m0 + r) * 256 + o] = f2bf(v > 0.f ? v : 0.f);
      }
    }
  }
}

// ---------------- S_part[ks] = Q @ K^T over K-chunk ks (4-way K-split), BK=64 ----------------
__global__ __launch_bounds__(256, 2) void k_scores(
    const unsigned short* __restrict__ qf, const unsigned short* __restrict__ kf,
    const int* __restrict__ gid, const int* __restrict__ seg, float* __restrict__ S) {
  const int mt = blockIdx.x, jt = blockIdx.y, ks = blockIdx.z;
  const int stride = seg[17];
  const int g_lo = gid[(mt * 128) * stride], g_hi = gid[(mt * 128 + 127) * stride];
  const int jlo = seg[g_lo], jhi = seg[g_hi + 1];
  if (jt * 128 >= jhi || jt * 128 + 128 <= jlo) return;

  __shared__ __align__(16) unsigned short lA[128 * 64];
  __shared__ __align__(16) unsigned short lB[128 * 64];
  const int tid = threadIdx.x;
  const int wave = tid >> 6, lane = tid & 63;
  const int wm = wave >> 1, wn = wave & 1;
  const int clog = (lane & 7) ^ ((lane >> 3) & 7);
  const unsigned short* ap[4];
  const unsigned short* bp[4];
#pragma unroll
  for (int s = 0; s < 4; s++) {
    int row = wave * 32 + s * 8 + (lane >> 3);
    ap[s] = qf + (mt * 128 + row) * 4096 + ks * 1024 + clog * 8;
    bp[s] = kf + (jt * 128 + row) * 4096 + ks * 1024 + clog * 8;
  }

  f32x4 acc[4][4];
  const f32x4 z = {0.f, 0.f, 0.f, 0.f};
#pragma unroll
  for (int i = 0; i < 4; i++)
#pragma unroll
    for (int j = 0; j < 4; j++) acc[i][j] = z;

  for (int kt = 0; kt < 16; kt++) {
    int off = kt * 64;
    __syncthreads();
#pragma unroll
    for (int s = 0; s < 4; s++) {
      stage16(ap[s] + off, lA + (wave * 32 + s * 8) * 64);
      stage16(bp[s] + off, lB + (wave * 32 + s * 8) * 64);
    }
    __syncthreads();
    mma_step64(lA, lB, acc, lane, wm, wn);
  }

  float* Sp = S + ks * 4194304;
  const int r15 = lane & 15, q4 = lane >> 4;
#pragma unroll
  for (int ni = 0; ni < 4; ni++) {
    int j = jt * 128 + wn * 64 + ni * 16 + r15;
#pragma unroll
    for (int mi = 0; mi < 4; mi++) {
      int m0 = mt * 128 + wm * 64 + mi * 16 + q4 * 4;
#pragma unroll
      for (int r = 0; r < 4; r++)
        Sp[(m0 + r) * 2048 + j] = acc[mi][ni][r];
    }
  }
}

// ---------------- per-row masked softmax over summed K-planes -> P (bf16) ----------------
__global__ void k_softmax(const float* __restrict__ S, const int* __restrict__ gid,
                          const int* __restrict__ seg, unsigned short* __restrict__ P) {
  const int m = blockIdx.x * 4 + (threadIdx.x >> 6);
  const int lane = threadIdx.x & 63;
  const int stride = seg[17];
  const int g = gid[m * stride];
  const int s0 = seg[g], e = seg[g + 1];
  const float scale = 0.04419417382415922f;   // 1/sqrt(512)
  const float* row = S + m * 2048;
  float mx = -3.0e38f;
  for (int j = s0 + lane; j < e; j += 64) {
    float v = row[j] + row[j + 4194304] + row[j + 8388608] + row[j + 12582912];
    mx = fmaxf(mx, v);
  }
#pragma unroll
  for (int off = 32; off > 0; off >>= 1) mx = fmaxf(mx, __shfl_xor(mx, off));
  float sum = 0.f;
  for (int j = s0 + lane; j < e; j += 64) {
    float v = row[j] + row[j + 4194304] + row[j + 8388608] + row[j + 12582912];
    sum += __expf((v - mx) * scale);
  }
#pragma unroll
  for (int off = 32; off > 0; off >>= 1) sum += __shfl_xor(sum, off);
  const float inv = 1.f / sum;
  unsigned short* prow = P + m * 2048;
  for (int j = s0 + lane; j < e; j += 64) {
    float v = row[j] + row[j + 4194304] + row[j + 8388608] + row[j + 12582912];
    prow[j] = f2bf(__expf((v - mx) * scale) * inv);
  }
}

// ---------------- vf [2048][4096] -> vT [4096][2048] ----------------
__global__ void k_transpose_v(const unsigned short* __restrict__ vf,
                              unsigned short* __restrict__ vT) {
  __shared__ unsigned short t[64][66];
  const int jt = blockIdx.x, dt = blockIdx.y;
  const int tid = threadIdx.x;
  const int r = tid >> 6, c = tid & 63;
#pragma unroll
  for (int i = 0; i < 16; i++) {
    int j = i * 4 + r;
    t[j][c] = vf[(jt * 64 + j) * 4096 + dt * 64 + c];
  }
  __syncthreads();
#pragma unroll
  for (int i = 0; i < 16; i++) {
    int d = i * 4 + r;
    vT[(dt * 64 + d) * 2048 + jt * 64 + c] = t[c][d];
  }
}

// ---------------- out = P @ V (ragged K per m-tile), BK=64, epilogue -> NCHW f32 ----------------
__global__ __launch_bounds__(256, 2) void k_pv(
    const unsigned short* __restrict__ P, const unsigned short* __restrict__ vT,
    const int* __restrict__ gid, const int* __restrict__ seg, float* __restrict__ out) {
  const int mt = blockIdx.x, dt = blockIdx.y;
  const int stride = seg[17];
  const int g_lo = gid[(mt * 128) * stride], g_hi = gid[(mt * 128 + 127) * stride];
  const int ks0 = seg[g_lo] & ~63;
  const int ke = seg[g_hi + 1];
  const int iters = (ke - ks0 + 63) >> 6;   // P==0 outside segments covers padding

  __shared__ __align__(16) unsigned short lA[128 * 64];
  __shared__ __align__(16) unsigned short lB[128 * 64];
  const int tid = threadIdx.x;
  const int wave = tid >> 6, lane = tid & 63;
  const int wm = wave >> 1, wn = wave & 1;
  const int clog = (lane & 7) ^ ((lane >> 3) & 7);
  const unsigned short* ap[4];
  const unsigned short* bp[4];
#pragma unroll
  for (int s = 0; s < 4; s++) {
    int row = wave * 32 + s * 8 + (lane >> 3);
    ap[s] = P + (mt * 128 + row) * 2048 + ks0 + clog * 8;
    bp[s] = vT + (dt * 128 + row) * 2048 + ks0 + clog * 8;
  }

  f32x4 acc[4][4];
  const f32x4 z = {0.f, 0.f, 0.f, 0.f};
#pragma unroll
  for (int i = 0; i < 4; i++)
#pragma unroll
    for (int j = 0; j < 4; j++) acc[i][j] = z;

  for (int kt = 0; kt < iters; kt++) {
    int off = kt * 64;
    __syncthreads();
#pragma unroll
    for (int s = 0; s < 4; s++) {
      stage16(ap[s] + off, lA + (wave * 32 + s * 8) * 64);
      stage16(bp[s] + off, lB + (wave * 32 + s * 8) * 64);
    }
    __syncthreads();
    mma_step64(lA, lB, acc, lane, wm, wn);
  }

  const int r15 = lane & 15, q4 = lane >> 4;
#pragma unroll
  for (int ni = 0; ni < 4; ni++) {
    int d = dt * 128 + wn * 64 + ni * 16 + r15;
    int c = d & 255, pix = d >> 8;   // our d = pix*256 + c; ref wants n*4096 + c*16 + pix
#pragma unroll
    for (int mi = 0; mi < 4; mi++) {
      int m0 = mt * 128 + wm * 64 + mi * 16 + q4 * 4;
#pragma unroll
      for (int r = 0; r < 4; r++)
        out[(m0 + r) * 4096 + c * 16 + pix] = acc[mi][ni][r];
    }
  }
}

extern "C" void kernel_launch(void* const* d_in, const int* in_sizes, int n_in,
                              void* d_out, int out_size, void* d_ws, size_t ws_size,
                              hipStream_t stream) {
  const float* x   = (const float*)d_in[0];
  const int*   gid = (const int*)d_in[1];
  const float* qw1 = (const float*)d_in[2];
  const float* qb1 = (const float*)d_in[3];
  const float* qw2 = (const float*)d_in[4];
  const float* qb2 = (const float*)d_in[5];
  const float* kw1 = (const float*)d_in[6];
  const float* kb1 = (const float*)d_in[7];
  const float* kw2 = (const float*)d_in[8];
  const float* kb2 = (const float*)d_in[9];
  const float* vw1 = (const float*)d_in[10];
  const float* vb1 = (const float*)d_in[11];
  const float* vw2 = (const float*)d_in[12];
  const float* vb2 = (const float*)d_in[13];

  char* ws = (char*)d_ws;
  unsigned short* xb  = (unsigned short*)(ws + XB_OFF);
  unsigned short* w1t = (unsigned short*)(ws + W1_OFF);
  unsigned short* w2t = (unsigned short*)(ws + W2_OFF);
  unsigned short* y1  = (unsigned short*)(ws + Y1_OFF);
  unsigned short* qkv = (unsigned short*)(ws + QKV_OFF);
  int* seg            = (int*)(ws + SEG_OFF);
  float* S            = (float*)(ws + S_OFF);
  unsigned short* P   = (unsigned short*)(ws + P_OFF);
  unsigned short* vT  = (unsigned short*)(ws + VT_OFF);
  const unsigned short* qf = qkv;
  const unsigned short* kf = qkv + 8388608;
  const unsigned short* vf = qkv + 16777216;

  static bool attr_set = false;
  if (!attr_set) {
    hipFuncSetAttribute((const void*)k_conv1,
                        hipFuncAttributeMaxDynamicSharedMemorySize, 131072);
    attr_set = true;
  }

  k_seg<<<1, 256, 0, stream>>>(gid, seg);
  k_convert_x<<<dim3(2048, 8), 256, 0, stream>>>(x, xb);
  k_convert_w<<<20736, 256, 0, stream>>>(qw1, kw1, vw1, qw2, kw2, vw2, w1t, w2t);
  k_conv1<<<dim3(864), 512, 131072, stream>>>(xb, w1t, qb1, kb1, vb1, y1);
  k_conv2<<<dim3(2, 3, 256), 256, 0, stream>>>(y1, w2t, qb2, kb2, vb2, qkv);
  hipMemsetAsync(P, 0, 8388608, stream);   // P zero outside segments (S/P/vT alias dead y1)
  k_scores<<<dim3(16, 16, 4), 256, 0, stream>>>(qf, kf, gid, seg, S);
  k_softmax<<<512, 256, 0, stream>>>(S, gid, seg, P);
  k_transpose_v<<<dim3(32, 64), 256, 0, stream>>>(vf, vT);
  k_pv<<<dim3(16, 32), 256, 0, stream>>>(P, vT, gid, seg, (float*)d_out);
}

// Round 3
// 1167.477 us; speedup vs baseline: 1.1329x; 1.0340x over previous
//
#include <hip/hip_runtime.h>
#include <hip/hip_bf16.h>

#define DI __device__ __forceinline__

typedef float f32x4 __attribute__((ext_vector_type(4)));
typedef __bf16 bf16x8 __attribute__((ext_vector_type(8)));

// ---------------- workspace layout (bytes) ----------------
#define XB_OFF   0ll                      // [2048][8][8][512] bf16  = 134217728
#define W1_OFF   134217728ll              // [768][4608] bf16        = 7077888
#define W2_OFF   141295616ll              // [768][2304] bf16        = 3538944
#define Y1_OFF   144834560ll              // [73728][768] bf16       = 113246208
#define QKV_OFF  258080768ll              // 3 x [32768][256] bf16   = 50331648
#define SEG_OFF  308412416ll              // 18 ints
// aliases inside the Y1 region (only used after conv2 is done):
#define S_OFF    (Y1_OFF)                 // 4 x [2048][2048] f32 = 67108864
#define P_OFF    (Y1_OFF + 67108864ll)    // [2048][2048] bf16    = 8388608
#define VT_OFF   (Y1_OFF + 75497472ll)    // [4096][2048] bf16    = 16777216

DI unsigned short f2bf(float f) {
  union { float f; unsigned u; } v; v.f = f;
  return (unsigned short)((v.u + 0x7FFFu + ((v.u >> 16) & 1u)) >> 16);
}

// async global->LDS, 16B per lane; LDS dest is wave-uniform base + lane*16
DI void stage16(const void* g, void* l) {
  __builtin_amdgcn_global_load_lds(
      (const __attribute__((address_space(1))) void*)(unsigned long long)g,
      (__attribute__((address_space(3))) void*)(unsigned long long)l,
      16, 0, 0);
}

// BK=64 LDS tile: [128 rows][8 chunks of 16B]; row stride = 128 B = full 32-bank span,
// so bank group depends only on chunk. Phys chunk = logical ^ (row&7):
//  - read: quarter-wave (16 lanes, rows 0..15, same logical chunk) spreads over
//    8 bank groups 2-way -> free (m136).
//  - staging lane l covers row (l>>3), phys chunk (l&7) -> clog=(l&7)^((l>>3)&7).
DI void mma_step64(const unsigned short* lA, const unsigned short* lB,
                   f32x4 acc[4][4], int lane, int wm, int wn) {
  const int r15 = lane & 15;
  const int cb = lane >> 4;            // k-subchunk within a 32-wide half
  const int rx = r15 & 7;
#pragma unroll
  for (int kh = 0; kh < 2; kh++) {
    const int ph = (kh * 4 + cb) ^ rx;
    bf16x8 af[4], bfr[4];
#pragma unroll
    for (int mi = 0; mi < 4; mi++)
      af[mi] = *(const bf16x8*)(lA + (wm * 64 + mi * 16 + r15) * 64 + ph * 8);
#pragma unroll
    for (int ni = 0; ni < 4; ni++)
      bfr[ni] = *(const bf16x8*)(lB + (wn * 64 + ni * 16 + r15) * 64 + ph * 8);
#pragma unroll
    for (int mi = 0; mi < 4; mi++)
#pragma unroll
      for (int ni = 0; ni < 4; ni++)
        acc[mi][ni] = __builtin_amdgcn_mfma_f32_16x16x32_bf16(af[mi], bfr[ni], acc[mi][ni], 0, 0, 0);
  }
}

// ---------------- segment offsets (+ int32/int64 layout detect) ----------------
__global__ void k_seg(const int* __restrict__ gid, int* __restrict__ seg) {
  __shared__ int cnt[16];
  int tid = threadIdx.x;
  if (tid < 16) cnt[tid] = 0;
  __syncthreads();
  int stride = (gid[2047] == 0) ? 2 : 1;
  for (int i = tid; i < 2048; i += 256) atomicAdd(&cnt[gid[i * stride]], 1);
  __syncthreads();
  if (tid == 0) {
    int s = 0;
    for (int g = 0; g < 16; g++) { seg[g] = s; s += cnt[g]; }
    seg[16] = s;
    seg[17] = stride;
  }
}

// ---------------- NCHW f32 -> NHWC bf16 ----------------
__global__ void k_convert_x(const float* __restrict__ x, unsigned short* __restrict__ xb) {
  __shared__ unsigned short t[64][66];   // [pixel][channel]
  const int n = blockIdx.x, cb = blockIdx.y;
  const int tid = threadIdx.x;
  const int cr = tid >> 6, p = tid & 63;
  const float* src = x + (n * 512 + cb * 64) * 64;
#pragma unroll
  for (int i = 0; i < 16; i++) {
    int c = i * 4 + cr;
    t[p][c] = f2bf(src[c * 64 + p]);
  }
  __syncthreads();
  unsigned* dst = (unsigned*)(xb + n * 32768 + cb * 64);
  const int pr = tid >> 5, c2 = tid & 31;
#pragma unroll
  for (int i = 0; i < 8; i++) {
    int p2 = i * 8 + pr;
    unsigned lo = t[p2][c2 * 2], hi = t[p2][c2 * 2 + 1];
    dst[p2 * 256 + c2] = lo | (hi << 16);
  }
}

// ---------------- weights: OIHW f32 -> [row][(ky,kx,cin)] bf16, fused w1+w2 ----------------
__global__ void k_convert_w(const float* __restrict__ qw1, const float* __restrict__ kw1,
                            const float* __restrict__ vw1, const float* __restrict__ qw2,
                            const float* __restrict__ kw2, const float* __restrict__ vw2,
                            unsigned short* __restrict__ w1t, unsigned short* __restrict__ w2t) {
  int idx = blockIdx.x * 256 + threadIdx.x;
  if (idx < 3538944) {                       // w1: 768 x 4608
    int row = idx / 4608, k = idx - row * 4608;
    int br = row >> 8, o = row & 255;
    int kk = k >> 9, cin = k & 511;
    int ky = kk / 3, kx = kk - ky * 3;
    const float* w = (br == 0) ? qw1 : (br == 1) ? kw1 : vw1;
    w1t[idx] = f2bf(w[((o * 512 + cin) * 3 + ky) * 3 + kx]);
  } else {                                   // w2: 768 x 2304
    idx -= 3538944;
    int row = idx / 2304, k = idx - row * 2304;
    int br = row >> 8, o = row & 255;
    int kk = k >> 8, c = k & 255;
    int ky = kk / 3, kx = kk - ky * 3;
    const float* w = (br == 0) ? qw2 : (br == 1) ? kw2 : vw2;
    w2t[idx] = f2bf(w[((o * 256 + c) * 3 + ky) * 3 + kx]);
  }
}

// A-tile K-offset for BK=64: kt in [0,72); kk = kt>>3 in [0,9)
DI int conv1_aoff64(int kt) {
  int kk = kt >> 3;
  int ky = (kk * 11) >> 5;        // kk/3 for kk<9
  int kx = kk - ky * 3;
  return (ky * 8 + kx) * 512 + (kt & 7) * 64;
}

// ---------------- conv1 implicit GEMM: M=73728 K=4608 N=768 ----------------
// m201-faithful 256x256 8-phase template: BK=64, 8 waves (2M x 4N, wave out 128x64),
// LDS = dbuf A[2][256][64] + B[2][256][64] = 128 KiB. Per K-tile: 4 phases with
// register-reuse rotation (A0B0 / A0B1 / A1B1 / A1B0; b0 held 4 phases -> phase d
// issues ZERO ds_reads).
// Staging schedule (race-audited): region X of buffer buf=t&1 may be staged for
// tile t+2 only after ALL tile-t reads of X complete:
//   A-half h is read by waves wm==h in phases a AND c  -> stageable in phase d only.
//   B halves are fully read by end of phase b          -> stageable in phase c/d.
// Issue order per iter: a: A-h1(t+1)[2]; c: B-h0(t+2)[2]; d: B-h1(t+2)+A-h0(t+2)[4],
// then s_waitcnt vmcnt(6) (6 newest = tile t+2's) -> tile t+1 landed. Never 0 until
// tail (t==70). lgkmcnt(0)+sched_barrier(0) pin MFMA clusters (rule 18); setprio(1)
// around MFMA (T5). Chunk swizzle phys = logical ^ (row&7) on both sides (rule 21).
// Bijective XCD swizzle (864 = 8*108, T1). Accumulation order identical to r0/r1.
__global__ __launch_bounds__(512, 2) void k_conv1(
    const unsigned short* __restrict__ xb, const unsigned short* __restrict__ w1t,
    const float* __restrict__ qb1, const float* __restrict__ kb1, const float* __restrict__ vb1,
    unsigned short* __restrict__ y1) {
  extern __shared__ __align__(16) unsigned short lds[];  // A: 2x16384 elems, B at 32768: 2x16384
  const int bswz = (blockIdx.x & 7) * 108 + (blockIdx.x >> 3);
  const int mt = bswz / 3, nt = bswz - mt * 3;           // 288 mt x 3 nt
  const int tid = threadIdx.x;
  const int wave = tid >> 6, lane = tid & 63;
  const int wm = wave >> 2, wn = wave & 3;               // wave out: rows wm*128, cols wn*64
  const int r15 = lane & 15, q4 = lane >> 4;

  // ---- staging sources (pre-swizzled chunk; wave-row layout: 2 instr x 8 rows per half) ----
  const int clog = (lane & 7) ^ ((lane >> 3) & 7);
  const unsigned short* aSrc[4];   // [h*2 + j]
#pragma unroll
  for (int h = 0; h < 2; h++)
#pragma unroll
    for (int j = 0; j < 2; j++) {
      int r = h * 128 + wave * 16 + j * 8 + (lane >> 3);
      int m = mt * 256 + r;
      int n = m / 36, pix = m - n * 36;
      int oy = pix / 6, ox = pix - oy * 6;
      aSrc[h * 2 + j] = xb + ((n * 8 + oy) * 8 + ox) * 512 + clog * 8;
    }
  const unsigned short* bSrc = w1t + (nt * 256 + wave * 16 + (lane >> 3)) * 4608 + clog * 8;

  // ---- per-lane ds_read offset (elements); kh toggles element bit 5 inside chunk field ----
  const int laneRd = r15 * 64 + ((q4 ^ (r15 & 7)) * 8);

  f32x4 acc[8][4];
  const f32x4 z = {0.f, 0.f, 0.f, 0.f};
#pragma unroll
  for (int i = 0; i < 8; i++)
#pragma unroll
    for (int j = 0; j < 4; j++) acc[i][j] = z;

#define FENCE() asm volatile("" ::: "memory")
#define BAR()   do { __builtin_amdgcn_s_barrier(); FENCE(); } while (0)
#define LGKM0() do { asm volatile("s_waitcnt lgkmcnt(0)" ::: "memory"); \
                     __builtin_amdgcn_sched_barrier(0); } while (0)

#define STG_A(kt_, h_, db_) do {                                              \
    const int ao_ = conv1_aoff64(kt_);                                        \
    unsigned short* d_ = lds + (db_) * 16384 + ((h_) * 128 + wave * 16) * 64; \
    stage16(aSrc[(h_) * 2 + 0] + ao_, d_);                                    \
    stage16(aSrc[(h_) * 2 + 1] + ao_, d_ + 512);                              \
  } while (0)

#define STG_B(kt_, h_, db_) do {                                              \
    const unsigned short* s_ = bSrc + (h_) * 589824 + (kt_) * 64;             \
    unsigned short* d_ = lds + 32768 + (db_) * 16384 + ((h_) * 128 + wave * 16) * 64; \
    stage16(s_, d_);                                                          \
    stage16(s_ + 36864, d_ + 512);                                            \
  } while (0)

  // ---- prologue: tile 0 complete (8 loads), then tile 1's B-h0, B-h1, A-h0 (6 loads)
  // in steady-state issue order (c: B-h0; d: B-h1, A-h0). A-h1(1) comes in phase a of t=0.
  STG_A(0, 0, 0); STG_A(0, 1, 0); STG_B(0, 0, 0); STG_B(0, 1, 0);
  STG_B(1, 0, 1); STG_B(1, 1, 1); STG_A(1, 0, 1);
  asm volatile("s_waitcnt vmcnt(6)" ::: "memory");   // oldest 8 = tile 0 landed
  __builtin_amdgcn_s_barrier();
  FENCE();

  bf16x8 af[4][2], b0[2][2], b1[2][2];

#pragma unroll 2
  for (int t = 0; t < 72; t++) {
    const int buf = t & 1;
    const unsigned short* At = lds + buf * 16384 + wm * 8192;
    const unsigned short* Bt = lds + 32768 + buf * 16384 + wn * 4096;

    // ---------- phase a: read A0(8) + B0(4); stage A-h1(t+1) [other buffer]; MFMA A0 x B0 ----------
#pragma unroll
    for (int f = 0; f < 4; f++)
#pragma unroll
      for (int kh = 0; kh < 2; kh++)
        af[f][kh] = *(const bf16x8*)(At + f * 1024 + (laneRd ^ (kh * 32)));
#pragma unroll
    for (int f = 0; f < 2; f++)
#pragma unroll
      for (int kh = 0; kh < 2; kh++)
        b0[f][kh] = *(const bf16x8*)(Bt + f * 1024 + (laneRd ^ (kh * 32)));
    FENCE();
    if (t < 71) STG_A(t + 1, 1, (t + 1) & 1);
    asm volatile("s_waitcnt lgkmcnt(8)" ::: "memory");
    __builtin_amdgcn_s_barrier();
    FENCE();
    LGKM0();
    __builtin_amdgcn_s_setprio(1);
#pragma unroll
    for (int f = 0; f < 4; f++)
#pragma unroll
      for (int n2 = 0; n2 < 2; n2++)
#pragma unroll
        for (int kh = 0; kh < 2; kh++)
          acc[f][n2] = __builtin_amdgcn_mfma_f32_16x16x32_bf16(af[f][kh], b0[n2][kh], acc[f][n2], 0, 0, 0);
    __builtin_amdgcn_s_setprio(0);
    BAR();

    // ---------- phase b: read B1(4); no staging; MFMA A0 x B1 ----------
#pragma unroll
    for (int f = 0; f < 2; f++)
#pragma unroll
      for (int kh = 0; kh < 2; kh++)
        b1[f][kh] = *(const bf16x8*)(Bt + (2 + f) * 1024 + (laneRd ^ (kh * 32)));
    FENCE();
    __builtin_amdgcn_s_barrier();
    FENCE();
    LGKM0();
    __builtin_amdgcn_s_setprio(1);
#pragma unroll
    for (int f = 0; f < 4; f++)
#pragma unroll
      for (int n2 = 0; n2 < 2; n2++)
#pragma unroll
        for (int kh = 0; kh < 2; kh++)
          acc[f][2 + n2] = __builtin_amdgcn_mfma_f32_16x16x32_bf16(af[f][kh], b1[n2][kh], acc[f][2 + n2], 0, 0, 0);
    __builtin_amdgcn_s_setprio(0);
    BAR();

    // ---------- phase c: read A1(8); stage B-h0(t+2) [B reads of tile t done]; MFMA A1 x B1 ----------
#pragma unroll
    for (int f = 0; f < 4; f++)
#pragma unroll
      for (int kh = 0; kh < 2; kh++)
        af[f][kh] = *(const bf16x8*)(At + 4096 + f * 1024 + (laneRd ^ (kh * 32)));
    FENCE();
    if (t < 70) STG_B(t + 2, 0, buf);
    __builtin_amdgcn_s_barrier();
    FENCE();
    LGKM0();
    __builtin_amdgcn_s_setprio(1);
#pragma unroll
    for (int f = 0; f < 4; f++)
#pragma unroll
      for (int n2 = 0; n2 < 2; n2++)
#pragma unroll
        for (int kh = 0; kh < 2; kh++)
          acc[4 + f][2 + n2] = __builtin_amdgcn_mfma_f32_16x16x32_bf16(af[f][kh], b1[n2][kh], acc[4 + f][2 + n2], 0, 0, 0);
    __builtin_amdgcn_s_setprio(0);
    BAR();

    // ---------- phase d: no reads; stage B-h1(t+2) + A-h0(t+2) [A reads of tile t done
    // as of phase-c barrier]; vmcnt(6); MFMA A1 x B0 ----------
    FENCE();
    if (t < 70) {
      STG_B(t + 2, 1, buf);
      STG_A(t + 2, 0, buf);
      asm volatile("s_waitcnt vmcnt(6)" ::: "memory");   // tile t+1 landed; tile t+2's 3 halves in flight
    } else if (t == 70) {
      asm volatile("s_waitcnt vmcnt(0)" ::: "memory");   // tail drain: tile 71 landed
    }
    __builtin_amdgcn_s_barrier();
    FENCE();
    __builtin_amdgcn_s_setprio(1);
#pragma unroll
    for (int f = 0; f < 4; f++)
#pragma unroll
      for (int n2 = 0; n2 < 2; n2++)
#pragma unroll
        for (int kh = 0; kh < 2; kh++)
          acc[4 + f][n2] = __builtin_amdgcn_mfma_f32_16x16x32_bf16(af[f][kh], b0[n2][kh], acc[4 + f][n2], 0, 0, 0);
    __builtin_amdgcn_s_setprio(0);
    BAR();
  }
#undef STG_A
#undef STG_B
#undef FENCE
#undef BAR
#undef LGKM0

  // ---- epilogue: bias + relu -> y1 ----
  const float* bias = (nt == 0) ? qb1 : (nt == 1) ? kb1 : vb1;
#pragma unroll
  for (int fn = 0; fn < 4; fn++) {
    const int col = nt * 256 + wn * 64 + fn * 16 + r15;
    const float bvv = bias[col & 255];
#pragma unroll
    for (int fm = 0; fm < 8; fm++) {
      const int m0 = mt * 256 + wm * 128 + fm * 16 + q4 * 4;
#pragma unroll
      for (int r = 0; r < 4; r++) {
        float v = acc[fm][fn][r] + bvv;
        y1[(m0 + r) * 768 + col] = f2bf(v > 0.f ? v : 0.f);
      }
    }
  }
}

// ---------------- conv2 implicit GEMM per branch: M=32768 K=2304 N=256, BK=64 ----------------
// grid (nt=2 fast, br=3, mt=256): 6 consecutive blocks share one A-tile.
__global__ __launch_bounds__(256, 2) void k_conv2(
    const unsigned short* __restrict__ y1, const unsigned short* __restrict__ w2t,
    const float* __restrict__ qb2, const float* __restrict__ kb2, const float* __restrict__ vb2,
    unsigned short* __restrict__ qkv) {
  __shared__ __align__(16) unsigned short lA[128 * 64];
  __shared__ __align__(16) unsigned short lB[128 * 64];
  const int nt = blockIdx.x, br = blockIdx.y, mt = blockIdx.z;
  const int tid = threadIdx.x;
  const int wave = tid >> 6, lane = tid & 63;
  const int wm = wave >> 1, wn = wave & 1;

  const int clog = (lane & 7) ^ ((lane >> 3) & 7);
  const unsigned short* ap[4];
  const unsigned short* bp[4];
#pragma unroll
  for (int s = 0; s < 4; s++) {
    int m = mt * 128 + wave * 32 + s * 8 + (lane >> 3);
    int n = m >> 4, pix = m & 15;
    int oy = pix >> 2, ox = pix & 3;
    ap[s] = y1 + (n * 36 + oy * 6 + ox) * 768 + br * 256 + clog * 8;
    int r = br * 256 + nt * 128 + wave * 32 + s * 8 + (lane >> 3);
    bp[s] = w2t + r * 2304 + clog * 8;
  }

  f32x4 acc[4][4];
  const f32x4 z = {0.f, 0.f, 0.f, 0.f};
#pragma unroll
  for (int i = 0; i < 4; i++)
#pragma unroll
    for (int j = 0; j < 4; j++) acc[i][j] = z;

  for (int kt = 0; kt < 36; kt++) {
    int kk = kt >> 2;
    int ky = kk / 3, kx = kk - ky * 3;
    int aoff = (ky * 6 + kx) * 768 + (kt & 3) * 64;
    int boff = kt * 64;
    __syncthreads();
#pragma unroll
    for (int s = 0; s < 4; s++) {
      stage16(ap[s] + aoff, lA + (wave * 32 + s * 8) * 64);
      stage16(bp[s] + boff, lB + (wave * 32 + s * 8) * 64);
    }
    __syncthreads();
    mma_step64(lA, lB, acc, lane, wm, wn);
  }

  const float* bias = (br == 0) ? qb2 : (br == 1) ? kb2 : vb2;
  unsigned short* outb = qkv + br * 8388608;
  const int r15 = lane & 15, q4 = lane >> 4;
#pragma unroll
  for (int ni = 0; ni < 4; ni++) {
    int o = nt * 128 + wn * 64 + ni * 16 + r15;
    float bv = bias[o];
#pragma unroll
    for (int mi = 0; mi < 4; mi++) {
      int m0 = mt * 128 + wm * 64 + mi * 16 + q4 * 4;
#pragma unroll
      for (int r = 0; r < 4; r++) {
        float v = acc[mi][ni][r] + bv;
        outb[(m0 + r) * 256 + o] = f2bf(v > 0.f ? v : 0.f);
      }
    }
  }
}

// ---------------- S_part[ks] = Q @ K^T over K-chunk ks (4-way K-split), BK=64 ----------------
__global__ __launch_bounds__(256, 2) void k_scores(
    const unsigned short* __restrict__ qf, const unsigned short* __restrict__ kf,
    const int* __restrict__ gid, const int* __restrict__ seg, float* __restrict__ S) {
  const int mt = blockIdx.x, jt = blockIdx.y, ks = blockIdx.z;
  const int stride = seg[17];
  const int g_lo = gid[(mt * 128) * stride], g_hi = gid[(mt * 128 + 127) * stride];
  const int jlo = seg[g_lo], jhi = seg[g_hi + 1];
  if (jt * 128 >= jhi || jt * 128 + 128 <= jlo) return;

  __shared__ __align__(16) unsigned short lA[128 * 64];
  __shared__ __align__(16) unsigned short lB[128 * 64];
  const int tid = threadIdx.x;
  const int wave = tid >> 6, lane = tid & 63;
  const int wm = wave >> 1, wn = wave & 1;
  const int clog = (lane & 7) ^ ((lane >> 3) & 7);
  const unsigned short* ap[4];
  const unsigned short* bp[4];
#pragma unroll
  for (int s = 0; s < 4; s++) {
    int row = wave * 32 + s * 8 + (lane >> 3);
    ap[s] = qf + (mt * 128 + row) * 4096 + ks * 1024 + clog * 8;
    bp[s] = kf + (jt * 128 + row) * 4096 + ks * 1024 + clog * 8;
  }

  f32x4 acc[4][4];
  const f32x4 z = {0.f, 0.f, 0.f, 0.f};
#pragma unroll
  for (int i = 0; i < 4; i++)
#pragma unroll
    for (int j = 0; j < 4; j++) acc[i][j] = z;

  for (int kt = 0; kt < 16; kt++) {
    int off = kt * 64;
    __syncthreads();
#pragma unroll
    for (int s = 0; s < 4; s++) {
      stage16(ap[s] + off, lA + (wave * 32 + s * 8) * 64);
      stage16(bp[s] + off, lB + (wave * 32 + s * 8) * 64);
    }
    __syncthreads();
    mma_step64(lA, lB, acc, lane, wm, wn);
  }

  float* Sp = S + ks * 4194304;
  const int r15 = lane & 15, q4 = lane >> 4;
#pragma unroll
  for (int ni = 0; ni < 4; ni++) {
    int j = jt * 128 + wn * 64 + ni * 16 + r15;
#pragma unroll
    for (int mi = 0; mi < 4; mi++) {
      int m0 = mt * 128 + wm * 64 + mi * 16 + q4 * 4;
#pragma unroll
      for (int r = 0; r < 4; r++)
        Sp[(m0 + r) * 2048 + j] = acc[mi][ni][r];
    }
  }
}

// ---------------- per-row masked softmax over summed K-planes -> P (bf16) ----------------
__global__ void k_softmax(const float* __restrict__ S, const int* __restrict__ gid,
                          const int* __restrict__ seg, unsigned short* __restrict__ P) {
  const int m = blockIdx.x * 4 + (threadIdx.x >> 6);
  const int lane = threadIdx.x & 63;
  const int stride = seg[17];
  const int g = gid[m * stride];
  const int s0 = seg[g], e = seg[g + 1];
  const float scale = 0.04419417382415922f;   // 1/sqrt(512)
  const float* row = S + m * 2048;
  float mx = -3.0e38f;
  for (int j = s0 + lane; j < e; j += 64) {
    float v = row[j] + row[j + 4194304] + row[j + 8388608] + row[j + 12582912];
    mx = fmaxf(mx, v);
  }
#pragma unroll
  for (int off = 32; off > 0; off >>= 1) mx = fmaxf(mx, __shfl_xor(mx, off));
  float sum = 0.f;
  for (int j = s0 + lane; j < e; j += 64) {
    float v = row[j] + row[j + 4194304] + row[j + 8388608] + row[j + 12582912];
    sum += __expf((v - mx) * scale);
  }
#pragma unroll
  for (int off = 32; off > 0; off >>= 1) sum += __shfl_xor(sum, off);
  const float inv = 1.f / sum;
  unsigned short* prow = P + m * 2048;
  for (int j = s0 + lane; j < e; j += 64) {
    float v = row[j] + row[j + 4194304] + row[j + 8388608] + row[j + 12582912];
    prow[j] = f2bf(__expf((v - mx) * scale) * inv);
  }
}

// ---------------- vf [2048][4096] -> vT [4096][2048] ----------------
__global__ void k_transpose_v(const unsigned short* __restrict__ vf,
                              unsigned short* __restrict__ vT) {
  __shared__ unsigned short t[64][66];
  const int jt = blockIdx.x, dt = blockIdx.y;
  const int tid = threadIdx.x;
  const int r = tid >> 6, c = tid & 63;
#pragma unroll
  for (int i = 0; i < 16; i++) {
    int j = i * 4 + r;
    t[j][c] = vf[(jt * 64 + j) * 4096 + dt * 64 + c];
  }
  __syncthreads();
#pragma unroll
  for (int i = 0; i < 16; i++) {
    int d = i * 4 + r;
    vT[(dt * 64 + d) * 2048 + jt * 64 + c] = t[c][d];
  }
}

// ---------------- out = P @ V (ragged K per m-tile), BK=64, epilogue -> NCHW f32 ----------------
__global__ __launch_bounds__(256, 2) void k_pv(
    const unsigned short* __restrict__ P, const unsigned short* __restrict__ vT,
    const int* __restrict__ gid, const int* __restrict__ seg, float* __restrict__ out) {
  const int mt = blockIdx.x, dt = blockIdx.y;
  const int stride = seg[17];
  const int g_lo = gid[(mt * 128) * stride], g_hi = gid[(mt * 128 + 127) * stride];
  const int ks0 = seg[g_lo] & ~63;
  const int ke = seg[g_hi + 1];
  const int iters = (ke - ks0 + 63) >> 6;   // P==0 outside segments covers padding

  __shared__ __align__(16) unsigned short lA[128 * 64];
  __shared__ __align__(16) unsigned short lB[128 * 64];
  const int tid = threadIdx.x;
  const int wave = tid >> 6, lane = tid & 63;
  const int wm = wave >> 1, wn = wave & 1;
  const int clog = (lane & 7) ^ ((lane >> 3) & 7);
  const unsigned short* ap[4];
  const unsigned short* bp[4];
#pragma unroll
  for (int s = 0; s < 4; s++) {
    int row = wave * 32 + s * 8 + (lane >> 3);
    ap[s] = P + (mt * 128 + row) * 2048 + ks0 + clog * 8;
    bp[s] = vT + (dt * 128 + row) * 2048 + ks0 + clog * 8;
  }

  f32x4 acc[4][4];
  const f32x4 z = {0.f, 0.f, 0.f, 0.f};
#pragma unroll
  for (int i = 0; i < 4; i++)
#pragma unroll
    for (int j = 0; j < 4; j++) acc[i][j] = z;

  for (int kt = 0; kt < iters; kt++) {
    int off = kt * 64;
    __syncthreads();
#pragma unroll
    for (int s = 0; s < 4; s++) {
      stage16(ap[s] + off, lA + (wave * 32 + s * 8) * 64);
      stage16(bp[s] + off, lB + (wave * 32 + s * 8) * 64);
    }
    __syncthreads();
    mma_step64(lA, lB, acc, lane, wm, wn);
  }

  const int r15 = lane & 15, q4 = lane >> 4;
#pragma unroll
  for (int ni = 0; ni < 4; ni++) {
    int d = dt * 128 + wn * 64 + ni * 16 + r15;
    int c = d & 255, pix = d >> 8;   // our d = pix*256 + c; ref wants n*4096 + c*16 + pix
#pragma unroll
    for (int mi = 0; mi < 4; mi++) {
      int m0 = mt * 128 + wm * 64 + mi * 16 + q4 * 4;
#pragma unroll
      for (int r = 0; r < 4; r++)
        out[(m0 + r) * 4096 + c * 16 + pix] = acc[mi][ni][r];
    }
  }
}

extern "C" void kernel_launch(void* const* d_in, const int* in_sizes, int n_in,
                              void* d_out, int out_size, void* d_ws, size_t ws_size,
                              hipStream_t stream) {
  const float* x   = (const float*)d_in[0];
  const int*   gid = (const int*)d_in[1];
  const float* qw1 = (const float*)d_in[2];
  const float* qb1 = (const float*)d_in[3];
  const float* qw2 = (const float*)d_in[4];
  const float* qb2 = (const float*)d_in[5];
  const float* kw1 = (const float*)d_in[6];
  const float* kb1 = (const float*)d_in[7];
  const float* kw2 = (const float*)d_in[8];
  const float* kb2 = (const float*)d_in[9];
  const float* vw1 = (const float*)d_in[10];
  const float* vb1 = (const float*)d_in[11];
  const float* vw2 = (const float*)d_in[12];
  const float* vb2 = (const float*)d_in[13];

  char* ws = (char*)d_ws;
  unsigned short* xb  = (unsigned short*)(ws + XB_OFF);
  unsigned short* w1t = (unsigned short*)(ws + W1_OFF);
  unsigned short* w2t = (unsigned short*)(ws + W2_OFF);
  unsigned short* y1  = (unsigned short*)(ws + Y1_OFF);
  unsigned short* qkv = (unsigned short*)(ws + QKV_OFF);
  int* seg            = (int*)(ws + SEG_OFF);
  float* S            = (float*)(ws + S_OFF);
  unsigned short* P   = (unsigned short*)(ws + P_OFF);
  unsigned short* vT  = (unsigned short*)(ws + VT_OFF);
  const unsigned short* qf = qkv;
  const unsigned short* kf = qkv + 8388608;
  const unsigned short* vf = qkv + 16777216;

  static bool attr_set = false;
  if (!attr_set) {
    hipFuncSetAttribute((const void*)k_conv1,
                        hipFuncAttributeMaxDynamicSharedMemorySize, 131072);
    attr_set = true;
  }

  k_seg<<<1, 256, 0, stream>>>(gid, seg);
  k_convert_x<<<dim3(2048, 8), 256, 0, stream>>>(x, xb);
  k_convert_w<<<20736, 256, 0, stream>>>(qw1, kw1, vw1, qw2, kw2, vw2, w1t, w2t);
  k_conv1<<<dim3(864), 512, 131072, stream>>>(xb, w1t, qb1, kb1, vb1, y1);
  k_conv2<<<dim3(2, 3, 256), 256, 0, stream>>>(y1, w2t, qb2, kb2, vb2, qkv);
  hipMemsetAsync(P, 0, 8388608, stream);   // P zero outside segments (S/P/vT alias dead y1)
  k_scores<<<dim3(16, 16, 4), 256, 0, stream>>>(qf, kf, gid, seg, S);
  k_softmax<<<512, 256, 0, stream>>>(S, gid, seg, P);
  k_transpose_v<<<dim3(32, 64), 256, 0, stream>>>(vf, vT);
  k_pv<<<dim3(16, 32), 256, 0, stream>>>(P, vT, gid, seg, (float*)d_out);
}